// Round 3
// baseline (794.789 us; speedup 1.0000x reference)
//
#include <hip/hip_runtime.h>
#include <cstdint>

typedef unsigned short u16;
typedef unsigned int   u32;
typedef unsigned long long u64;

typedef short bf16x8 __attribute__((ext_vector_type(8)));
typedef float f32x4  __attribute__((ext_vector_type(4)));

#define BM 128
#define BN 128
#define BK 64

__device__ __forceinline__ u32 pack2bf(float a, float b) {
    // [a -> low u16, b -> high u16], round-half-up bf16
    const u32 ua = __builtin_bit_cast(u32, a) + 0x8000u;
    const u32 ub = __builtin_bit_cast(u32, b) + 0x8000u;
    return (ub & 0xFFFF0000u) | (ua >> 16);
}

// Fixed problem: M=8192, N=4096, K=4096, G=32 (gsize=128)
// x, scales, bias, y are FLOAT32 buffers (harness promotes fp16 -> f32).
__global__ __launch_bounds__(256, 2) void gptq_gemm_kernel(
    const float* __restrict__ X,    // [M, K] f32
    const int* __restrict__ QW,     // [N, K/8] int32, 8 nibbles LSB-first along K
    const int* __restrict__ QZ,     // [G, N/8] int32, 8 nibbles LSB-first along N
    const float* __restrict__ SC,   // [G, N] f32
    const float* __restrict__ BIAS, // [N] f32
    float* __restrict__ Y)          // [M, N] f32
{
    constexpr int M = 8192, N = 4096, K = 4096, G = 32;
    constexpr int KB = K / 8;  // 512 int32 per qweight row

    __shared__ __align__(16) u16 Alds[BM * BK];   // [128][64] x tile (bf16 bits)
    __shared__ __align__(16) u16 Blds[BN * BK];   // [128][64] dequant W tile (row n, col k)

    const int tid  = threadIdx.x;
    const int lane = tid & 63;
    const int wid  = tid >> 6;

    const int m0 = blockIdx.x * BM;  // gridDim.x = 64
    const int n0 = blockIdx.y * BN;  // gridDim.y = 32

    // ---- accumulators: 4 waves in 2x2, each wave 64x64 = 4x4 16x16 frags ----
    f32x4 acc[4][4];
#pragma unroll
    for (int i = 0; i < 4; i++)
#pragma unroll
        for (int j = 0; j < 4; j++)
            acc[i][j] = (f32x4){0.f, 0.f, 0.f, 0.f};

    const int wm = (wid >> 1) * 64;   // wave row offset in block tile
    const int wn = (wid & 1) * 64;    // wave col offset

    // per-thread A staging map: 8 f32 -> 8 bf16 (16B LDS) per slab of 32 rows
    const int lrowA = tid >> 3;          // 0..31
    const int lcolA = (tid & 7) * 8;     // element offset (8 floats)
    const float* gA = X + (u64)(m0 + lrowA) * K + lcolA;

    // per-thread B staging map: thread -> (n_local = tid/2, 4 int32 half = (tid&1)*4)
    const int nl  = tid >> 1;            // 0..127
    const int kq0 = (tid & 1) * 4;       // which 4 of the 8 int32 per row-slab
    const int nglob = n0 + nl;
    const int* qrow = QW + (u64)nglob * KB;

    // MFMA fragment addressing
    const int fr = lane & 15;            // frag row/col index (m for A, n for B)
    const int fq = (lane >> 4) * 8;      // k sub-offset (quad*8)

    for (int g = 0; g < G; ++g) {
        // per-group dequant constants for this thread's n-row (L2-resident loads)
        const float sf = SC[g * N + nglob];
        const int   zw = QZ[g * (N / 8) + (nglob >> 3)];
        const float zf = (float)((zw >> ((nglob & 7) * 4)) & 0xF);
        const float nzs = -zf * sf;

#pragma unroll
        for (int t = 0; t < 2; ++t) {
            const int kt = g * 128 + t * 64;

            __syncthreads();   // previous tile fully consumed

            // ---- issue all global loads first ----
            float4 af32[8];
#pragma unroll
            for (int i = 0; i < 4; i++) {
                const float* pa = gA + (u64)i * 32 * K + kt;
                af32[2 * i]     = *(const float4*)pa;
                af32[2 * i + 1] = *(const float4*)(pa + 4);
            }
            const int4 q4 = *(const int4*)(qrow + (kt >> 3) + kq0);

            // ---- A: convert f32 -> bf16, write 16B per slab ----
#pragma unroll
            for (int i = 0; i < 4; i++) {
                const float4 f0 = af32[2 * i], f1 = af32[2 * i + 1];
                uint4 w;
                w.x = pack2bf(f0.x, f0.y);
                w.y = pack2bf(f0.z, f0.w);
                w.z = pack2bf(f1.x, f1.y);
                w.w = pack2bf(f1.z, f1.w);
                *(uint4*)(&Alds[i * 2048 + tid * 8]) = w;
            }

            // ---- B: dequant 32 int4 values, write 4 x 16B ----
            {
                const int qv[4] = {q4.x, q4.y, q4.z, q4.w};
#pragma unroll
                for (int c = 0; c < 4; c++) {
                    const u32 q  = (u32)qv[c];
                    const u32 lo = q & 0x0F0F0F0Fu;         // nibbles j=0,2,4,6
                    const u32 hi = (q >> 4) & 0x0F0F0F0Fu;  // nibbles j=1,3,5,7
                    uint4 w;
                    u32 p[4];
#pragma unroll
                    for (int b = 0; b < 4; b++) {
                        const float fe = fmaf((float)((lo >> (8 * b)) & 0xFFu), sf, nzs);
                        const float fo = fmaf((float)((hi >> (8 * b)) & 0xFFu), sf, nzs);
                        p[b] = pack2bf(fe, fo);
                    }
                    w.x = p[0]; w.y = p[1]; w.z = p[2]; w.w = p[3];
                    *(uint4*)(&Blds[nl * BK + (kq0 + c) * 8]) = w;
                }
            }

            __syncthreads();   // all LDS writes visible

            // ---- compute: 2 K-steps of 16 MFMAs ----
#pragma unroll
            for (int ks = 0; ks < 2; ks++) {
                const int qk = ks * 32 + fq;
                bf16x8 af[4], bfr[4];
#pragma unroll
                for (int i = 0; i < 4; i++)
                    af[i] = *(const bf16x8*)(&Alds[(wm + i * 16 + fr) * BK + qk]);
#pragma unroll
                for (int i = 0; i < 4; i++)
                    bfr[i] = *(const bf16x8*)(&Blds[(wn + i * 16 + fr) * BK + qk]);
#pragma unroll
                for (int mi = 0; mi < 4; mi++)
#pragma unroll
                    for (int ni = 0; ni < 4; ni++)
                        acc[mi][ni] = __builtin_amdgcn_mfma_f32_16x16x32_bf16(
                            af[mi], bfr[ni], acc[mi][ni], 0, 0, 0);
            }
        }
    }

    // ---- epilogue: + bias, store f32. C/D map: col=lane&15, row=quad*4+reg ----
    const int cn  = lane & 15;
    const int q4r = (lane >> 4) * 4;
#pragma unroll
    for (int ni = 0; ni < 4; ni++) {
        const int col = n0 + wn + ni * 16 + cn;
        const float bz = BIAS[col];
#pragma unroll
        for (int mi = 0; mi < 4; mi++) {
            const int rbase = m0 + wm + mi * 16 + q4r;
#pragma unroll
            for (int r = 0; r < 4; r++) {
                Y[(u64)(rbase + r) * N + col] = acc[mi][ni][r] + bz;
            }
        }
    }
}

extern "C" void kernel_launch(void* const* d_in, const int* in_sizes, int n_in,
                              void* d_out, int out_size, void* d_ws, size_t ws_size,
                              hipStream_t stream) {
    const float* X    = (const float*)d_in[0];   // x       [2,4096,4096] f32 (fp16 promoted)
    const int*   QW   = (const int*)d_in[1];     // qweight [4096,512] int32
    const int*   QZ   = (const int*)d_in[2];     // qzeros  [32,512] int32
    const float* SC   = (const float*)d_in[3];   // scales  [32,4096] f32
    const float* BIAS = (const float*)d_in[4];   // bias    [4096] f32
    float* Y = (float*)d_out;                    // [8192,4096] f32

    dim3 grid(64, 32, 1);   // M/128 x N/128
    gptq_gemm_kernel<<<grid, 256, 0, stream>>>(X, QW, QZ, SC, BIAS, Y);
}

// Round 5
// 677.471 us; speedup vs baseline: 1.1732x; 1.1732x over previous
//
#include <hip/hip_runtime.h>
#include <cstdint>

typedef unsigned short u16;
typedef unsigned int   u32;
typedef unsigned long long u64;

typedef _Float16 f16x2 __attribute__((ext_vector_type(2)));
typedef _Float16 f16x8 __attribute__((ext_vector_type(8)));
typedef float    f32x4 __attribute__((ext_vector_type(4)));

#define BM 128
#define BN 128
#define BK 64

// pack two f32 into fp16x2 bits (RTZ is fine: inputs are exactly fp16-representable)
__device__ __forceinline__ u32 cvt_pk(float a, float b) {
    return __builtin_bit_cast(u32, __builtin_amdgcn_cvt_pkrtz(a, b));
}

// Fixed problem: M=8192, N=4096, K=4096, G=32 (gsize=128)
// x, scales, bias, y are FLOAT32 buffers (harness promotes fp16 -> f32; values
// are exactly fp16-representable, so cvt back to fp16 is exact).
//
// LDS tile layout: [row][8 granules of 8 fp16], granule g of row r stored at
// u16 offset r*64 + ((g ^ (r&7))*8)  -- XOR swizzle kills bank conflicts.
// Within each granule, k-order is [0,4,1,5,2,6,3,7] (matches the nibble-pair
// magic unpack); applied identically to A and B, so MFMA's k-contraction is
// unaffected.
__global__ __launch_bounds__(256, 2) void gptq_gemm_kernel(
    const float* __restrict__ X,    // [M, K] f32
    const int* __restrict__ QW,     // [N, K/8] int32, 8 nibbles LSB-first along K
    const int* __restrict__ QZ,     // [G, N/8] int32, 8 nibbles LSB-first along N
    const float* __restrict__ SC,   // [G, N] f32
    const float* __restrict__ BIAS, // [N] f32
    float* __restrict__ Y)          // [M, N] f32
{
    constexpr int M = 8192, N = 4096, K = 4096, G = 32;
    constexpr int KB = K / 8;  // 512 int32 per qweight row

    __shared__ __align__(16) u16 Alds[BM * BK];   // fp16 bits, swizzled
    __shared__ __align__(16) u16 Blds[BN * BK];   // fp16 bits, swizzled

    const int tid  = threadIdx.x;
    const int lane = tid & 63;
    const int wid  = tid >> 6;

    const int m0 = blockIdx.x * BM;  // gridDim.x = 64
    const int n0 = blockIdx.y * BN;  // gridDim.y = 32

    f32x4 acc[4][4];
#pragma unroll
    for (int i = 0; i < 4; i++)
#pragma unroll
        for (int j = 0; j < 4; j++)
            acc[i][j] = (f32x4){0.f, 0.f, 0.f, 0.f};

    const int wm = (wid >> 1) * 64;   // wave row offset in block tile
    const int wn = (wid & 1) * 64;    // wave col offset

    // A staging: thread covers rows {lrowA + 32i}, 8 floats at lcolA
    const int lrowA = tid >> 3;               // 0..31
    const int lcolA = (tid & 7) * 8;          // k offset within tile
    const float* gA = X + (u64)(m0 + lrowA) * K + lcolA;
    const int sA = ((tid & 7) ^ (lrowA & 7)) * 8;   // swizzled granule offset (u16)

    // B staging: thread -> n_local = tid/2, int32 half = (tid&1)*4
    const int nl  = tid >> 1;                 // 0..127
    const int kq0 = (tid & 1) * 4;
    const int nglob = n0 + nl;
    const int* qrow = QW + (u64)nglob * KB;
    const int nl7 = nl & 7;

    // MFMA fragment addressing
    const int fr   = lane & 15;               // frag row (m for A, n for B)
    const int quad = lane >> 4;               // 0..3
    const int fr7  = fr & 7;

    for (int g = 0; g < G; ++g) {
        // per-group dequant constants for this thread's n-row
        const float sf = SC[g * N + nglob];
        const int   zw = QZ[g * (N / 8) + (nglob >> 3)];
        const int   z  = (zw >> ((nglob & 7) * 4)) & 0xF;
        const _Float16 hs = (_Float16)sf;                // exact (scale was fp16)
        const _Float16 hz = (_Float16)(float)(1024 + z); // exact integer
        const f16x2 cs = {hs, hs};
        const f16x2 cz = {hz, hz};

#pragma unroll
        for (int t = 0; t < 2; ++t) {
            const int kt = g * 128 + t * 64;

            __syncthreads();   // previous tile fully consumed

            // ---- issue all global loads first ----
            float4 af32[8];
#pragma unroll
            for (int i = 0; i < 4; i++) {
                const float* pa = gA + (u64)i * 32 * K + kt;
                af32[2 * i]     = *(const float4*)pa;
                af32[2 * i + 1] = *(const float4*)(pa + 4);
            }
            const int4 q4 = *(const int4*)(qrow + (kt >> 3) + kq0);

            // ---- A: f32 -> fp16 (exact), interleave (0,4),(1,5),(2,6),(3,7) ----
#pragma unroll
            for (int i = 0; i < 4; i++) {
                const float4 f0 = af32[2 * i], f1 = af32[2 * i + 1];
                uint4 w;
                w.x = cvt_pk(f0.x, f1.x);
                w.y = cvt_pk(f0.y, f1.y);
                w.z = cvt_pk(f0.z, f1.z);
                w.w = cvt_pk(f0.w, f1.w);
                *(uint4*)(&Alds[(i * 32 + lrowA) * 64 + sA]) = w;
            }

            // ---- B: magic unpack -> exact fp16 dequant, 4 x 16B swizzled ----
            {
                const int qv[4] = {q4.x, q4.y, q4.z, q4.w};
#pragma unroll
                for (int c = 0; c < 4; c++) {
                    const u32 q = (u32)qv[c];
                    const u32 b0 = (q & 0x000F000Fu) | 0x64006400u;         // nib0,nib4
                    const u32 b1 = ((q >> 4) & 0x000F000Fu) | 0x64006400u;  // nib1,nib5
                    const u32 b2 = ((q >> 8) & 0x000F000Fu) | 0x64006400u;  // nib2,nib6
                    const u32 b3 = ((q >> 12) & 0x000F000Fu) | 0x64006400u; // nib3,nib7
                    const f16x2 w0 = (__builtin_bit_cast(f16x2, b0) - cz) * cs;
                    const f16x2 w1 = (__builtin_bit_cast(f16x2, b1) - cz) * cs;
                    const f16x2 w2 = (__builtin_bit_cast(f16x2, b2) - cz) * cs;
                    const f16x2 w3 = (__builtin_bit_cast(f16x2, b3) - cz) * cs;
                    uint4 w;
                    w.x = __builtin_bit_cast(u32, w0);
                    w.y = __builtin_bit_cast(u32, w1);
                    w.z = __builtin_bit_cast(u32, w2);
                    w.w = __builtin_bit_cast(u32, w3);
                    const int gran = ((kq0 + c) ^ nl7) * 8;
                    *(uint4*)(&Blds[nl * 64 + gran]) = w;
                }
            }

            __syncthreads();   // all LDS writes visible

            // ---- compute: 2 K-steps of 16 MFMAs ----
#pragma unroll
            for (int ks = 0; ks < 2; ks++) {
                const int chunk = ks * 4 + quad;
                const int gsw = (chunk ^ fr7) * 8;    // swizzled granule offset
                f16x8 af[4], bfr[4];
#pragma unroll
                for (int i = 0; i < 4; i++)
                    af[i] = *(const f16x8*)(&Alds[(wm + i * 16 + fr) * 64 + gsw]);
#pragma unroll
                for (int i = 0; i < 4; i++)
                    bfr[i] = *(const f16x8*)(&Blds[(wn + i * 16 + fr) * 64 + gsw]);
#pragma unroll
                for (int mi = 0; mi < 4; mi++)
#pragma unroll
                    for (int ni = 0; ni < 4; ni++)
                        acc[mi][ni] = __builtin_amdgcn_mfma_f32_16x16x32_f16(
                            af[mi], bfr[ni], acc[mi][ni], 0, 0, 0);
            }
        }
    }

    // ---- epilogue: + bias, store f32. C/D map: col=lane&15, row=quad*4+reg ----
    const int cn  = lane & 15;
    const int q4r = quad * 4;
#pragma unroll
    for (int ni = 0; ni < 4; ni++) {
        const int col = n0 + wn + ni * 16 + cn;
        const float bz = BIAS[col];
#pragma unroll
        for (int mi = 0; mi < 4; mi++) {
            const int rbase = m0 + wm + mi * 16 + q4r;
#pragma unroll
            for (int r = 0; r < 4; r++) {
                Y[(u64)(rbase + r) * N + col] = acc[mi][ni][r] + bz;
            }
        }
    }
}

extern "C" void kernel_launch(void* const* d_in, const int* in_sizes, int n_in,
                              void* d_out, int out_size, void* d_ws, size_t ws_size,
                              hipStream_t stream) {
    const float* X    = (const float*)d_in[0];   // x       [2,4096,4096] f32 (fp16 promoted)
    const int*   QW   = (const int*)d_in[1];     // qweight [4096,512] int32
    const int*   QZ   = (const int*)d_in[2];     // qzeros  [32,512] int32
    const float* SC   = (const float*)d_in[3];   // scales  [32,4096] f32
    const float* BIAS = (const float*)d_in[4];   // bias    [4096] f32
    float* Y = (float*)d_out;                    // [8192,4096] f32

    dim3 grid(64, 32, 1);   // M/128 x N/128
    gptq_gemm_kernel<<<grid, 256, 0, stream>>>(X, QW, QZ, SC, BIAS, Y);
}